// Round 11
// baseline (207.404 us; speedup 1.0000x reference)
//
#include <hip/hip_runtime.h>
#include <math.h>

#define BB 32
#define NN 8732
#define CC 21
#define TOPK 200
#define NPOSE 32
#define NLINE 3
#define NBINS 2048
#define CAP 1024
#define ROWW 40
#define NT 512   // 8 waves/block

// ---------------------------------------------------------------------------
// Full-precision f64 exp (degree-12 Horner), |rel err| ~1e-15.
// ---------------------------------------------------------------------------
__device__ __forceinline__ double fexp12(double x) {
  const double LOG2E = 1.4426950408889634074;
  const double LN2HI = 6.93147180369123816490e-01;
  const double LN2LO = 1.90821492927058770002e-10;
  double kd = rint(x * LOG2E);
  double r = fma(-kd, LN2HI, x);
  r = fma(-kd, LN2LO, r);
  double p = 2.08767569878680989792e-09;
  p = fma(p, r, 2.50521083854417187751e-08);
  p = fma(p, r, 2.75573192239858906526e-07);
  p = fma(p, r, 2.75573192239858925110e-06);
  p = fma(p, r, 2.48015873015873015873e-05);
  p = fma(p, r, 1.98412698412698412698e-04);
  p = fma(p, r, 1.38888888888888888889e-03);
  p = fma(p, r, 8.33333333333333333333e-03);
  p = fma(p, r, 4.16666666666666666667e-02);
  p = fma(p, r, 1.66666666666666666667e-01);
  p = fma(p, r, 0.5);
  p = fma(p, r, 1.0);
  p = fma(p, r, 1.0);
  int k = (int)kd;
  k = k < -1020 ? -1020 : (k > 1020 ? 1020 : k);
  double sc = __longlong_as_double((long long)(1023 + k) << 52);
  return p * sc;  // exact pow2 mul == ldexp(p,k)
}

// ---------------------------------------------------------------------------
// Hot-path f64 exp via 64-entry LDS table, |rel err| ~3e-13 (selection-safe).
// ---------------------------------------------------------------------------
__device__ __forceinline__ double fexp_t(double x, const double* __restrict__ T) {
  const double INV64 = 1.4426950408889634074 * 64.0;
  const double L64HI = 6.93147180369123816490e-01 / 64.0;
  const double L64LO = 1.90821492927058770002e-10 / 64.0;
  double kd = rint(x * INV64);
  double r = fma(-kd, L64HI, x);
  r = fma(-kd, L64LO, r);
  double p = 4.16666666666666666667e-02;
  p = fma(p, r, 1.66666666666666666667e-01);
  p = fma(p, r, 0.5);
  p = fma(p, r, 1.0);
  p = fma(p, r, 1.0);
  int ki = (int)kd;
  double t = T[ki & 63];
  int e = ki >> 6;
  e = e < -1020 ? -1020 : e;
  double sc = __longlong_as_double((long long)(1023 + e) << 52);
  return (t * p) * sc;
}

// ---------------------------------------------------------------------------
// scores[b][c][n] = softmax(conf)[b][n][c]; exact-f32 pipeline, transposed.
// c=0 slab is never read by nms (class 0 output is forced to zero), so the
// store loop starts at c=1: -1/21 write traffic.
// ---------------------------------------------------------------------------
__global__ __launch_bounds__(256, 4) void score_kernel(
    const float* __restrict__ conf, float* __restrict__ scores) {
  __shared__ __align__(16) float buf[256 * CC];
  __shared__ double Texp[64];
  const int tid = threadIdx.x;
  const int i0 = blockIdx.x * 256;
  const int base = i0 * CC;
  int total = BB * NN * CC - base;
  if (total > 256 * CC) total = 256 * CC;
  {
    const float4* g4 = (const float4*)(conf + base);
    float4* b4 = (float4*)buf;
    const int n4 = total >> 2;
    for (int t = tid; t < n4; t += 256) b4[t] = g4[t];
  }
  if (tid < 64)
    Texp[tid] = fexp12((double)tid * (6.93147180369123816490e-01 / 64.0));
  __syncthreads();
  const int i = i0 + tid;
  if (i >= BB * NN) return;
  const float* p = buf + tid * CC;
  float x[CC];
#pragma unroll
  for (int c = 0; c < CC; ++c) x[c] = p[c];
  float m = x[0];
#pragma unroll
  for (int c = 1; c < CC; ++c) m = fmaxf(m, x[c]);
  float e[CC];
#pragma unroll
  for (int c = 0; c < CC; ++c) e[c] = (float)fexp_t((double)(x[c] - m), Texp);
  float r0 = e[0] + e[8], r1 = e[1] + e[9], r2 = e[2] + e[10], r3 = e[3] + e[11];
  float r4 = e[4] + e[12], r5 = e[5] + e[13], r6 = e[6] + e[14], r7 = e[7] + e[15];
  float sum = ((r0 + r1) + (r2 + r3)) + ((r4 + r5) + (r6 + r7));
  sum += e[16]; sum += e[17]; sum += e[18]; sum += e[19]; sum += e[20];
  const int b = i / NN, n = i - b * NN;
#pragma unroll
  for (int c = 1; c < CC; ++c)  // c=0 never read
    scores[((size_t)b * CC + c) * NN + n] = e[c] / sum;  // true f32 divide
}

__device__ __forceinline__ int score_bin(float s) {
  unsigned u = __float_as_uint(s);
  int bin = (int)(u >> 15) - 30720;
  return bin < 0 ? 0 : (bin > NBINS - 1 ? NBINS - 1 : bin);
}

// Mode-0 fallback: full softmax score straight from conf.
__device__ __forceinline__ float score_full(const float* conf, int b, int c, int n) {
  const float* p = conf + ((size_t)b * NN + n) * CC;
  float mm = p[0];
  for (int c2 = 1; c2 < CC; ++c2) mm = fmaxf(mm, p[c2]);
  float e[CC];
  for (int c2 = 0; c2 < CC; ++c2) e[c2] = (float)fexp12((double)(p[c2] - mm));
  float r0 = e[0] + e[8], r1 = e[1] + e[9], r2 = e[2] + e[10], r3 = e[3] + e[11];
  float r4 = e[4] + e[12], r5 = e[5] + e[13], r6 = e[6] + e[14], r7 = e[7] + e[15];
  float sum = ((r0 + r1) + (r2 + r3)) + ((r4 + r5) + (r6 + r7));
  sum += e[16]; sum += e[17]; sum += e[18]; sum += e[19]; sum += e[20];
  return e[c] / sum;
}

// 64-bit wave-uniform broadcast from lane sl (sl must be wave-uniform).
__device__ __forceinline__ unsigned long long rl64(unsigned long long v, int sl) {
  unsigned lo = (unsigned)__builtin_amdgcn_readlane((int)(unsigned)(v & 0xFFFFFFFFull), sl);
  unsigned hi = (unsigned)__builtin_amdgcn_readlane((int)(unsigned)(v >> 32), sl);
  return ((unsigned long long)hi << 32) | (unsigned long long)lo;
}

// ---------------------------------------------------------------------------
// One 512-thread block per (b,c). Phase chain: load -> hist -> scan ->
// collect -> rank+decode -> supp (+pose/line L2 prefetch) ->
// [wave0: register greedy  ||  waves1-7: stage pose/line K rows into LDS] ->
// float4-packed per-row epilogue reading pose/line from LDS.
// ---------------------------------------------------------------------------
__global__ __launch_bounds__(NT, 4) void nms_kernel(
    const float* __restrict__ loc, const float* __restrict__ conf,
    const float* __restrict__ pose, const float* __restrict__ line,
    const float* __restrict__ dbox, const float* __restrict__ scores,
    int mode, float* __restrict__ out) {
  const int bc = blockIdx.x;
  const int b = bc / CC, c = bc - b * CC;
  const int tid = threadIdx.x;
  const int wv = tid >> 6, lane = tid & 63;
  float* outSlab = out + (size_t)bc * (TOPK * ROWW);
  const float4 z4 = make_float4(0.f, 0.f, 0.f, 0.f);

  if (c == 0) {  // out.at[:, 0].set(0.0)
    float4* o4 = (float4*)outSlab;
    for (int i = tid; i < TOPK * ROWW / 4; i += NT) o4[i] = z4;
    return;
  }

  __shared__ int hist[NBINS];
  __shared__ __align__(16) unsigned long long ckey[CAP + 16];
  __shared__ float4 cbox[TOPK];
  __shared__ float sScore[TOPK];
  __shared__ int sIdx[TOPK];
  __shared__ __align__(32) unsigned long long supp[TOPK * 4];
  __shared__ int kept[TOPK];
  __shared__ int waveTot[8];
  __shared__ int sBT, sCnt, sKept;
  __shared__ __align__(16) float4 poseStage[TOPK][8];  // 25.6 KB
  __shared__ float lineStage[TOPK][3];                 // 2.4 KB

  const float* scoresB = scores + ((size_t)b * CC + c) * NN;
  const float* poseB = pose + (size_t)b * NN * NPOSE;
  const float* lineB = line + (size_t)b * NN * NLINE;

  // ---- issue score loads FIRST (latency overlaps hist init + barrier) ----
  float4 v[5];
  if (mode == 1) {
#pragma unroll
    for (int k = 0; k < 4; ++k)
      v[k] = *(const float4*)(scoresB + k * 2048 + tid * 4);
    if (tid < 135)  // 8732 - 8192 = 540 = 135*4
      v[4] = *(const float4*)(scoresB + 8192 + tid * 4);
    else
      v[4] = make_float4(-1.f, -1.f, -1.f, -1.f);
  } else {
#pragma unroll 1
    for (int k = 0; k < 5; ++k) {
      const int n0 = (k < 4 ? k * 2048 : 8192) + (tid << 2);
      if (k < 4 || tid < 135) {
        v[k].x = score_full(conf, b, c, n0 + 0);
        v[k].y = score_full(conf, b, c, n0 + 1);
        v[k].z = score_full(conf, b, c, n0 + 2);
        v[k].w = score_full(conf, b, c, n0 + 3);
      } else {
        v[k] = make_float4(-1.f, -1.f, -1.f, -1.f);
      }
    }
  }

  for (int i = tid; i < NBINS; i += NT) hist[i] = 0;
  if (tid == 0) { sCnt = 0; sBT = 0; }
  __syncthreads();

  // ---- histogram on f32 score bit-pattern (monotone for s>0) ----
#pragma unroll
  for (int k = 0; k < 5; ++k) {
    if (v[k].x > 0.01f) atomicAdd(&hist[score_bin(v[k].x)], 1);
    if (v[k].y > 0.01f) atomicAdd(&hist[score_bin(v[k].y)], 1);
    if (v[k].z > 0.01f) atomicAdd(&hist[score_bin(v[k].z)], 1);
    if (v[k].w > 0.01f) atomicAdd(&hist[score_bin(v[k].w)], 1);
  }
  __syncthreads();

  // ---- threshold-bin: 4 bins/thread, wave suffix-scan + crossing thread ----
  int s4 = hist[tid * 4] + hist[tid * 4 + 1] + hist[tid * 4 + 2] + hist[tid * 4 + 3];
  int cs = s4;
#pragma unroll
  for (int d = 1; d < 64; d <<= 1) {
    int t = __shfl_down(cs, d, 64);
    if (lane + d < 64) cs += t;
  }
  if (lane == 0) waveTot[wv] = cs;
  __syncthreads();
  {
    int higher = 0;
    for (int g = wv + 1; g < 8; ++g) higher += waveTot[g];
    int incl = cs + higher;
    int excl = incl - s4;
    if (excl < TOPK && incl >= TOPK) {  // unique crossing thread
      int cum = excl, bt = tid * 4;
      for (int bin = tid * 4 + 3;; --bin) {
        cum += hist[bin];
        if (cum >= TOPK || bin == tid * 4) { bt = bin; break; }
      }
      sBT = bt;
    }
  }
  __syncthreads();
  const int bt = sBT;

  // ---- collect candidate keys from registers ----
#pragma unroll
  for (int k = 0; k < 5; ++k) {
    float sv[4] = {v[k].x, v[k].y, v[k].z, v[k].w};
#pragma unroll
    for (int j = 0; j < 4; ++j) {
      float s = sv[j];
      if (s > 0.01f && score_bin(s) >= bt) {
        int p = atomicAdd(&sCnt, 1);
        if (p < CAP) {
          unsigned n = (unsigned)((k < 4 ? k * 2048 : 8192) + (tid << 2) + j);
          ckey[p] = ((unsigned long long)__float_as_uint(s) << 32) |
                    (unsigned long long)(0xFFFFFFFFu - n);
        }
      }
    }
  }
  __syncthreads();
  const int M = sCnt < CAP ? sCnt : CAP;
  if (M == 0) {
    float4* o4 = (float4*)outSlab;
    for (int i = tid; i < TOPK * ROWW / 4; i += NT) o4[i] = z4;
    return;
  }
  const int K = M < TOPK ? M : TOPK;
  const int Mpad = (M + 15) & ~15;
  for (int i = M + tid; i < Mpad; i += NT) ckey[i] = 0ull;  // rank-neutral pad
  __syncthreads();

  // ---- fused rank-sort + decode: gathers issued before the rank loop, so
  //      their ~900cy latency hides under the LDS compare loop ----
  const float* locB = loc + (size_t)b * NN * 4;
  for (int t = tid; t < M; t += NT) {
    unsigned long long kt = ckey[t];
    unsigned n = 0xFFFFFFFFu - (unsigned)(kt & 0xFFFFFFFFull);
    float4 l4 = *(const float4*)(locB + (size_t)n * 4);   // early issue
    float4 d4 = *(const float4*)(dbox + (size_t)n * 4);   // early issue
    int r = 0;
    for (int j0 = 0; j0 < Mpad; j0 += 8) {
      ulonglong2 kk[4];
#pragma unroll
      for (int q = 0; q < 4; ++q)
        kk[q] = *(const ulonglong2*)(ckey + j0 + 2 * q);
#pragma unroll
      for (int q = 0; q < 4; ++q) {
        r += (kk[q].x > kt) ? 1 : 0;
        r += (kk[q].y > kt) ? 1 : 0;
      }
    }
    if (r < TOPK) {  // keys unique -> ranks unique
      // decode, f32, reference op order
      float cx = d4.x + (l4.x * 0.1f) * d4.z;
      float cy = d4.y + (l4.y * 0.1f) * d4.w;
      float w = d4.z * (float)fexp12((double)(l4.z * 0.2f));
      float h = d4.w * (float)fexp12((double)(l4.w * 0.2f));
      float x1 = cx - w * 0.5f;
      float y1 = cy - h * 0.5f;
      float x2 = x1 + w;
      float y2 = y1 + h;
      cbox[r] = make_float4(x1, y1, x2, y2);
      sScore[r] = __uint_as_float((unsigned)(kt >> 32));
      sIdx[r] = (int)n;
    }
  }
  __syncthreads();

  // ---- pose/line L2 prefetch: one dword probe per 64B sector of every
  //      candidate row, issued BEFORE supp so the ~900cy HBM latency hides
  //      under it; the staging pass after supp then hits L2. ----
  if (tid < 2 * TOPK) {
    const int row = tid >> 1;
    if (row < K) {
      const int n = sIdx[row];
      float pp = poseB[(size_t)n * NPOSE + (tid & 1) * 16];
      float ll = lineB[(size_t)n * NLINE + (tid & 1) * 2];
      asm volatile("" :: "v"(pp), "v"(ll));
    }
  }

  // ---- supp matrix: 8 waves = 4 l-words x 2 j-halves; divide-free IoU ----
  // RN_f32(inter/uni) > 0.45f  <=>  fma(-TMID, uni, inter) > 0 in double,
  // TMID = (double)0.45f + 2^-26 (midpoint; ties round-to-even -> false).
  // Areas recomputed from boxes: bit-identical to reference's area values.
  {
    const double TMID = (double)0.45f + 0x1p-26;
    const int lw = wv & 3, half = wv >> 2;
    const int l = lw * 64 + lane;
    const bool lvalid = l < K;
    float4 lb = lvalid ? cbox[l] : z4;
    float lar = (lb.z - lb.x) * (lb.w - lb.y);
    const int jlim = (K < lw * 64 + 63) ? K : (lw * 64 + 63);
    const int jmid = jlim >> 1;
    const int jstart = half ? jmid : 0;
    const int jend = half ? jlim : jmid;
    for (int j0 = jstart; j0 < jend; j0 += 4) {
      const int jc = (jend - j0 < 4) ? (jend - j0) : 4;
      float4 jb[4];
#pragma unroll
      for (int q = 0; q < 4; ++q)
        if (q < jc) jb[q] = cbox[j0 + q];
      unsigned long long mres[4];
#pragma unroll
      for (int q = 0; q < 4; ++q) {
        if (q < jc) {  // jc wave-uniform
          float ja = (jb[q].z - jb[q].x) * (jb[q].w - jb[q].y);
          float xx1 = fmaxf(lb.x, jb[q].x);
          float yy1 = fmaxf(lb.y, jb[q].y);
          float xx2 = fminf(lb.z, jb[q].z);
          float yy2 = fminf(lb.w, jb[q].w);
          float iw = fmaxf(xx2 - xx1, 0.0f);
          float ih = fmaxf(yy2 - yy1, 0.0f);
          float inter = iw * ih;
          float uni = (lar - inter) + ja;  // area - inter + area[i]
          double tt = fma(-TMID, (double)uni, (double)inter);
          bool hit = lvalid & (l > (j0 + q)) & (tt > 0.0);
          mres[q] = __ballot((int)hit);
        }
      }
      if (lane == 0) {
#pragma unroll
        for (int q = 0; q < 4; ++q)
          if (q < jc) supp[(j0 + q) * 4 + lw] = mres[q];
      }
    }
    if (half == 1 && lane == 0)
      for (int j = jlim; j < K; ++j) supp[j * 4 + lw] = 0ull;
  }
  __syncthreads();

  // ---- wave0: chunk-register greedy  ||  waves 1-7: stage pose/line into
  //      LDS for all K candidates (2 threads/row, 4 float4 each; loads hit
  //      L2 thanks to the earlier prefetch probes). Disjoint LDS/state. ----
  if (wv == 0) {
    unsigned long long a0, a1, a2, a3;
    {
      int c0 = K, c1 = K - 64, c2 = K - 128, c3 = K - 192;
      a0 = c0 <= 0 ? 0ull : (c0 >= 64 ? ~0ull : ((1ull << c0) - 1ull));
      a1 = c1 <= 0 ? 0ull : (c1 >= 64 ? ~0ull : ((1ull << c1) - 1ull));
      a2 = c2 <= 0 ? 0ull : (c2 >= 64 ? ~0ull : ((1ull << c2) - 1ull));
      a3 = c3 <= 0 ? 0ull : (c3 >= 64 ? ~0ull : ((1ull << c3) - 1ull));
    }
    unsigned long long k0 = 0ull, k1 = 0ull, k2 = 0ull, k3 = 0ull;
    const ulonglong2 zz = make_ulonglong2(0ull, 0ull);
    const ulonglong2* sp = (const ulonglong2*)supp;

#define GREEDY_CHUNK(W, AW, KW)                                              \
    if (AW) {                                                                \
      const int r = (W) * 64 + lane;                                         \
      ulonglong2 s01 = zz, s23 = zz;                                         \
      if (r < K) { s01 = sp[r * 2]; s23 = sp[r * 2 + 1]; }                   \
      while (AW) {                                                           \
        int sl = __ffsll(AW) - 1;                                            \
        KW |= 1ull << sl;                                                    \
        AW &= ~(1ull << sl);                                                 \
        unsigned long long q0 = rl64(s01.x, sl);                             \
        unsigned long long q1 = rl64(s01.y, sl);                             \
        unsigned long long q2 = rl64(s23.x, sl);                             \
        unsigned long long q3 = rl64(s23.y, sl);                             \
        a0 &= ~q0; a1 &= ~q1; a2 &= ~q2; a3 &= ~q3;                          \
      }                                                                      \
    }

    GREEDY_CHUNK(0, a0, k0)
    GREEDY_CHUNK(1, a1, k1)
    GREEDY_CHUNK(2, a2, k2)
    GREEDY_CHUNK(3, a3, k3)
#undef GREEDY_CHUNK

    // parallel compaction: kept[] in ascending rank order (== greedy order)
    const unsigned long long lmask = (1ull << lane) - 1ull;
    const int c0 = __popcll(k0), c1 = __popcll(k1), c2 = __popcll(k2);
    if ((k0 >> lane) & 1ull) kept[__popcll(k0 & lmask)] = lane;
    if ((k1 >> lane) & 1ull) kept[c0 + __popcll(k1 & lmask)] = 64 + lane;
    if ((k2 >> lane) & 1ull) kept[c0 + c1 + __popcll(k2 & lmask)] = 128 + lane;
    if ((k3 >> lane) & 1ull) kept[c0 + c1 + c2 + __popcll(k3 & lmask)] = 192 + lane;
    if (lane == 0) sKept = c0 + c1 + c2 + __popcll(k3);
  } else {
    // waves 1-7: 448 threads, 2 per candidate row (224 rows/pass >= K)
    const int t7 = tid - 64;        // 0..447
    const int row = t7 >> 1;
    const int h = t7 & 1;           // which half of the 8 float4s
    if (row < K) {
      const int n = sIdx[row];
      const float4* p4 = (const float4*)(poseB + (size_t)n * NPOSE);
#pragma unroll
      for (int q = 0; q < 4; ++q) poseStage[row][h * 4 + q] = p4[h * 4 + q];
      if (h == 0) {
        lineStage[row][0] = lineB[(size_t)n * NLINE + 0];
        lineStage[row][1] = lineB[(size_t)n * NLINE + 1];
        lineStage[row][2] = lineB[(size_t)n * NLINE + 2];
      }
    }
  }
  __syncthreads();

  // ---- float4-packed per-row epilogue, all operands from LDS ----
  const int nk = sKept;
  for (int t = tid; t < nk; t += NT) {
    int j = kept[t];
    float4* row4 = (float4*)(outSlab + (size_t)t * ROWW);
    float4 bx = cbox[j];
    float4 pv[8];
#pragma unroll
    for (int q = 0; q < 8; ++q) pv[q] = poseStage[j][q];
    float l0 = lineStage[j][0];
    float l1 = lineStage[j][1];
    float l2 = lineStage[j][2];
    float sc = sScore[j];
    row4[0] = make_float4(sc, bx.x, bx.y, bx.z);
    row4[1] = make_float4(bx.w, pv[0].x, pv[0].y, pv[0].z);
    row4[2] = make_float4(pv[0].w, pv[1].x, pv[1].y, pv[1].z);
    row4[3] = make_float4(pv[1].w, pv[2].x, pv[2].y, pv[2].z);
    row4[4] = make_float4(pv[2].w, pv[3].x, pv[3].y, pv[3].z);
    row4[5] = make_float4(pv[3].w, pv[4].x, pv[4].y, pv[4].z);
    row4[6] = make_float4(pv[4].w, pv[5].x, pv[5].y, pv[5].z);
    row4[7] = make_float4(pv[5].w, pv[6].x, pv[6].y, pv[6].z);
    row4[8] = make_float4(pv[6].w, pv[7].x, pv[7].y, pv[7].z);
    row4[9] = make_float4(pv[7].w, l0, l1, l2);
  }
  {  // rows [nk, TOPK): 10 float4 per row
    const int zq = (TOPK - nk) * 10;
    float4* o4 = (float4*)(outSlab + (size_t)nk * ROWW);
    for (int q = tid; q < zq; q += NT) o4[q] = z4;
  }
}

// ---------------------------------------------------------------------------
extern "C" void kernel_launch(void* const* d_in, const int* in_sizes, int n_in,
                              void* d_out, int out_size, void* d_ws, size_t ws_size,
                              hipStream_t stream) {
  const float* loc  = (const float*)d_in[0];
  const float* conf = (const float*)d_in[1];
  const float* pose = (const float*)d_in[2];
  const float* line = (const float*)d_in[3];
  const float* dbox = (const float*)d_in[4];
  float* out = (float*)d_out;

  const size_t scoreBytes = (size_t)BB * CC * NN * sizeof(float);  // ~23.5 MB
  int mode = (ws_size >= scoreBytes) ? 1 : 0;
  float* scores = mode ? (float*)d_ws : nullptr;

  if (mode) {
    const int total = BB * NN;
    score_kernel<<<(total + 255) / 256, 256, 0, stream>>>(conf, scores);
  }
  nms_kernel<<<BB * CC, NT, 0, stream>>>(loc, conf, pose, line, dbox,
                                         scores, mode, out);
}

// Round 12
// 177.589 us; speedup vs baseline: 1.1679x; 1.1679x over previous
//
#include <hip/hip_runtime.h>
#include <math.h>

#define BB 32
#define NN 8732
#define CC 21
#define TOPK 200
#define NPOSE 32
#define NLINE 3
#define NBINS 2048
#define CAP 1024
#define ROWW 40
#define NT 512   // 8 waves/block

// ---------------------------------------------------------------------------
// Full-precision f64 exp (degree-12 Horner), |rel err| ~1e-15.
// ---------------------------------------------------------------------------
__device__ __forceinline__ double fexp12(double x) {
  const double LOG2E = 1.4426950408889634074;
  const double LN2HI = 6.93147180369123816490e-01;
  const double LN2LO = 1.90821492927058770002e-10;
  double kd = rint(x * LOG2E);
  double r = fma(-kd, LN2HI, x);
  r = fma(-kd, LN2LO, r);
  double p = 2.08767569878680989792e-09;
  p = fma(p, r, 2.50521083854417187751e-08);
  p = fma(p, r, 2.75573192239858906526e-07);
  p = fma(p, r, 2.75573192239858925110e-06);
  p = fma(p, r, 2.48015873015873015873e-05);
  p = fma(p, r, 1.98412698412698412698e-04);
  p = fma(p, r, 1.38888888888888888889e-03);
  p = fma(p, r, 8.33333333333333333333e-03);
  p = fma(p, r, 4.16666666666666666667e-02);
  p = fma(p, r, 1.66666666666666666667e-01);
  p = fma(p, r, 0.5);
  p = fma(p, r, 1.0);
  p = fma(p, r, 1.0);
  int k = (int)kd;
  k = k < -1020 ? -1020 : (k > 1020 ? 1020 : k);
  double sc = __longlong_as_double((long long)(1023 + k) << 52);
  return p * sc;  // exact pow2 mul == ldexp(p,k)
}

// ---------------------------------------------------------------------------
// Hot-path f64 exp via 64-entry LDS table, |rel err| ~3e-13 (selection-safe).
// ---------------------------------------------------------------------------
__device__ __forceinline__ double fexp_t(double x, const double* __restrict__ T) {
  const double INV64 = 1.4426950408889634074 * 64.0;
  const double L64HI = 6.93147180369123816490e-01 / 64.0;
  const double L64LO = 1.90821492927058770002e-10 / 64.0;
  double kd = rint(x * INV64);
  double r = fma(-kd, L64HI, x);
  r = fma(-kd, L64LO, r);
  double p = 4.16666666666666666667e-02;
  p = fma(p, r, 1.66666666666666666667e-01);
  p = fma(p, r, 0.5);
  p = fma(p, r, 1.0);
  p = fma(p, r, 1.0);
  int ki = (int)kd;
  double t = T[ki & 63];
  int e = ki >> 6;
  e = e < -1020 ? -1020 : e;
  double sc = __longlong_as_double((long long)(1023 + e) << 52);
  return (t * p) * sc;
}

// ---------------------------------------------------------------------------
// scores[b][c][n] = softmax(conf)[b][n][c]; exact-f32 pipeline, transposed.
// c=0 slab is never read by nms (class-0 output is forced to zero), so the
// store loop starts at c=1 (proven-pass in r11; -1/21 write traffic).
// ---------------------------------------------------------------------------
__global__ __launch_bounds__(256, 4) void score_kernel(
    const float* __restrict__ conf, float* __restrict__ scores) {
  __shared__ __align__(16) float buf[256 * CC];
  __shared__ double Texp[64];
  const int tid = threadIdx.x;
  const int i0 = blockIdx.x * 256;
  const int base = i0 * CC;
  int total = BB * NN * CC - base;
  if (total > 256 * CC) total = 256 * CC;
  {
    const float4* g4 = (const float4*)(conf + base);
    float4* b4 = (float4*)buf;
    const int n4 = total >> 2;
    for (int t = tid; t < n4; t += 256) b4[t] = g4[t];
  }
  if (tid < 64)
    Texp[tid] = fexp12((double)tid * (6.93147180369123816490e-01 / 64.0));
  __syncthreads();
  const int i = i0 + tid;
  if (i >= BB * NN) return;
  const float* p = buf + tid * CC;
  float x[CC];
#pragma unroll
  for (int c = 0; c < CC; ++c) x[c] = p[c];
  float m = x[0];
#pragma unroll
  for (int c = 1; c < CC; ++c) m = fmaxf(m, x[c]);
  float e[CC];
#pragma unroll
  for (int c = 0; c < CC; ++c) e[c] = (float)fexp_t((double)(x[c] - m), Texp);
  float r0 = e[0] + e[8], r1 = e[1] + e[9], r2 = e[2] + e[10], r3 = e[3] + e[11];
  float r4 = e[4] + e[12], r5 = e[5] + e[13], r6 = e[6] + e[14], r7 = e[7] + e[15];
  float sum = ((r0 + r1) + (r2 + r3)) + ((r4 + r5) + (r6 + r7));
  sum += e[16]; sum += e[17]; sum += e[18]; sum += e[19]; sum += e[20];
  const int b = i / NN, n = i - b * NN;
#pragma unroll
  for (int c = 1; c < CC; ++c)  // c=0 never read
    scores[((size_t)b * CC + c) * NN + n] = e[c] / sum;  // true f32 divide
}

__device__ __forceinline__ int score_bin(float s) {
  unsigned u = __float_as_uint(s);
  int bin = (int)(u >> 15) - 30720;
  return bin < 0 ? 0 : (bin > NBINS - 1 ? NBINS - 1 : bin);
}

// Mode-0 fallback: full softmax score straight from conf.
__device__ __forceinline__ float score_full(const float* conf, int b, int c, int n) {
  const float* p = conf + ((size_t)b * NN + n) * CC;
  float mm = p[0];
  for (int c2 = 1; c2 < CC; ++c2) mm = fmaxf(mm, p[c2]);
  float e[CC];
  for (int c2 = 0; c2 < CC; ++c2) e[c2] = (float)fexp12((double)(p[c2] - mm));
  float r0 = e[0] + e[8], r1 = e[1] + e[9], r2 = e[2] + e[10], r3 = e[3] + e[11];
  float r4 = e[4] + e[12], r5 = e[5] + e[13], r6 = e[6] + e[14], r7 = e[7] + e[15];
  float sum = ((r0 + r1) + (r2 + r3)) + ((r4 + r5) + (r6 + r7));
  sum += e[16]; sum += e[17]; sum += e[18]; sum += e[19]; sum += e[20];
  return e[c] / sum;
}

// 64-bit wave-uniform broadcast from lane sl (sl must be wave-uniform).
__device__ __forceinline__ unsigned long long rl64(unsigned long long v, int sl) {
  unsigned lo = (unsigned)__builtin_amdgcn_readlane((int)(unsigned)(v & 0xFFFFFFFFull), sl);
  unsigned hi = (unsigned)__builtin_amdgcn_readlane((int)(unsigned)(v >> 32), sl);
  return ((unsigned long long)hi << 32) | (unsigned long long)lo;
}

// ---------------------------------------------------------------------------
// One 512-thread block per (b,c). Phase chain: load -> hist -> scan ->
// collect -> rank+decode -> supp (+pose/line L2 prefetch) ->
// wave0 chunk-register greedy -> float4-packed per-row epilogue.
// (= round-10 measured best: nms 74.0us, bench 177.8us.)
// ---------------------------------------------------------------------------
__global__ __launch_bounds__(NT, 4) void nms_kernel(
    const float* __restrict__ loc, const float* __restrict__ conf,
    const float* __restrict__ pose, const float* __restrict__ line,
    const float* __restrict__ dbox, const float* __restrict__ scores,
    int mode, float* __restrict__ out) {
  const int bc = blockIdx.x;
  const int b = bc / CC, c = bc - b * CC;
  const int tid = threadIdx.x;
  const int wv = tid >> 6, lane = tid & 63;
  float* outSlab = out + (size_t)bc * (TOPK * ROWW);
  const float4 z4 = make_float4(0.f, 0.f, 0.f, 0.f);

  if (c == 0) {  // out.at[:, 0].set(0.0)
    float4* o4 = (float4*)outSlab;
    for (int i = tid; i < TOPK * ROWW / 4; i += NT) o4[i] = z4;
    return;
  }

  __shared__ int hist[NBINS];
  __shared__ __align__(16) unsigned long long ckey[CAP + 16];
  __shared__ float4 cbox[TOPK];
  __shared__ float sScore[TOPK];
  __shared__ int sIdx[TOPK];
  __shared__ __align__(32) unsigned long long supp[TOPK * 4];
  __shared__ int kept[TOPK];
  __shared__ int waveTot[8];
  __shared__ int sBT, sCnt, sKept;

  const float* scoresB = scores + ((size_t)b * CC + c) * NN;
  const float* poseB = pose + (size_t)b * NN * NPOSE;
  const float* lineB = line + (size_t)b * NN * NLINE;

  // ---- issue score loads FIRST (latency overlaps hist init + barrier) ----
  float4 v[5];
  if (mode == 1) {
#pragma unroll
    for (int k = 0; k < 4; ++k)
      v[k] = *(const float4*)(scoresB + k * 2048 + tid * 4);
    if (tid < 135)  // 8732 - 8192 = 540 = 135*4
      v[4] = *(const float4*)(scoresB + 8192 + tid * 4);
    else
      v[4] = make_float4(-1.f, -1.f, -1.f, -1.f);
  } else {
#pragma unroll 1
    for (int k = 0; k < 5; ++k) {
      const int n0 = (k < 4 ? k * 2048 : 8192) + (tid << 2);
      if (k < 4 || tid < 135) {
        v[k].x = score_full(conf, b, c, n0 + 0);
        v[k].y = score_full(conf, b, c, n0 + 1);
        v[k].z = score_full(conf, b, c, n0 + 2);
        v[k].w = score_full(conf, b, c, n0 + 3);
      } else {
        v[k] = make_float4(-1.f, -1.f, -1.f, -1.f);
      }
    }
  }

  for (int i = tid; i < NBINS; i += NT) hist[i] = 0;
  if (tid == 0) { sCnt = 0; sBT = 0; }
  __syncthreads();

  // ---- histogram on f32 score bit-pattern (monotone for s>0) ----
#pragma unroll
  for (int k = 0; k < 5; ++k) {
    if (v[k].x > 0.01f) atomicAdd(&hist[score_bin(v[k].x)], 1);
    if (v[k].y > 0.01f) atomicAdd(&hist[score_bin(v[k].y)], 1);
    if (v[k].z > 0.01f) atomicAdd(&hist[score_bin(v[k].z)], 1);
    if (v[k].w > 0.01f) atomicAdd(&hist[score_bin(v[k].w)], 1);
  }
  __syncthreads();

  // ---- threshold-bin: 4 bins/thread, wave suffix-scan + crossing thread ----
  int s4 = hist[tid * 4] + hist[tid * 4 + 1] + hist[tid * 4 + 2] + hist[tid * 4 + 3];
  int cs = s4;
#pragma unroll
  for (int d = 1; d < 64; d <<= 1) {
    int t = __shfl_down(cs, d, 64);
    if (lane + d < 64) cs += t;
  }
  if (lane == 0) waveTot[wv] = cs;
  __syncthreads();
  {
    int higher = 0;
    for (int g = wv + 1; g < 8; ++g) higher += waveTot[g];
    int incl = cs + higher;
    int excl = incl - s4;
    if (excl < TOPK && incl >= TOPK) {  // unique crossing thread
      int cum = excl, bt = tid * 4;
      for (int bin = tid * 4 + 3;; --bin) {
        cum += hist[bin];
        if (cum >= TOPK || bin == tid * 4) { bt = bin; break; }
      }
      sBT = bt;
    }
  }
  __syncthreads();
  const int bt = sBT;

  // ---- collect candidate keys from registers ----
#pragma unroll
  for (int k = 0; k < 5; ++k) {
    float sv[4] = {v[k].x, v[k].y, v[k].z, v[k].w};
#pragma unroll
    for (int j = 0; j < 4; ++j) {
      float s = sv[j];
      if (s > 0.01f && score_bin(s) >= bt) {
        int p = atomicAdd(&sCnt, 1);
        if (p < CAP) {
          unsigned n = (unsigned)((k < 4 ? k * 2048 : 8192) + (tid << 2) + j);
          ckey[p] = ((unsigned long long)__float_as_uint(s) << 32) |
                    (unsigned long long)(0xFFFFFFFFu - n);
        }
      }
    }
  }
  __syncthreads();
  const int M = sCnt < CAP ? sCnt : CAP;
  if (M == 0) {
    float4* o4 = (float4*)outSlab;
    for (int i = tid; i < TOPK * ROWW / 4; i += NT) o4[i] = z4;
    return;
  }
  const int K = M < TOPK ? M : TOPK;
  const int Mpad = (M + 15) & ~15;
  for (int i = M + tid; i < Mpad; i += NT) ckey[i] = 0ull;  // rank-neutral pad
  __syncthreads();

  // ---- fused rank-sort + decode: gathers issued before the rank loop, so
  //      their ~900cy latency hides under the LDS compare loop ----
  const float* locB = loc + (size_t)b * NN * 4;
  for (int t = tid; t < M; t += NT) {
    unsigned long long kt = ckey[t];
    unsigned n = 0xFFFFFFFFu - (unsigned)(kt & 0xFFFFFFFFull);
    float4 l4 = *(const float4*)(locB + (size_t)n * 4);   // early issue
    float4 d4 = *(const float4*)(dbox + (size_t)n * 4);   // early issue
    int r = 0;
    for (int j0 = 0; j0 < Mpad; j0 += 8) {
      ulonglong2 kk[4];
#pragma unroll
      for (int q = 0; q < 4; ++q)
        kk[q] = *(const ulonglong2*)(ckey + j0 + 2 * q);
#pragma unroll
      for (int q = 0; q < 4; ++q) {
        r += (kk[q].x > kt) ? 1 : 0;
        r += (kk[q].y > kt) ? 1 : 0;
      }
    }
    if (r < TOPK) {  // keys unique -> ranks unique
      // decode, f32, reference op order
      float cx = d4.x + (l4.x * 0.1f) * d4.z;
      float cy = d4.y + (l4.y * 0.1f) * d4.w;
      float w = d4.z * (float)fexp12((double)(l4.z * 0.2f));
      float h = d4.w * (float)fexp12((double)(l4.w * 0.2f));
      float x1 = cx - w * 0.5f;
      float y1 = cy - h * 0.5f;
      float x2 = x1 + w;
      float y2 = y1 + h;
      cbox[r] = make_float4(x1, y1, x2, y2);
      sScore[r] = __uint_as_float((unsigned)(kt >> 32));
      sIdx[r] = (int)n;
    }
  }
  __syncthreads();

  // ---- pose/line L2 prefetch: one dword probe per 64B sector of every
  //      candidate row, issued BEFORE supp+greedy so the ~900cy HBM latency
  //      hides under them. asm keeps the dead loads alive (no DCE).
  //      Same lines the epilogue reads -> zero extra HBM bytes. ----
  if (tid < 2 * TOPK) {
    const int row = tid >> 1;
    if (row < K) {
      const int n = sIdx[row];
      float pp = poseB[(size_t)n * NPOSE + (tid & 1) * 16];
      float ll = lineB[(size_t)n * NLINE + (tid & 1) * 2];
      asm volatile("" :: "v"(pp), "v"(ll));
    }
  }

  // ---- supp matrix: 8 waves = 4 l-words x 2 j-halves; divide-free IoU ----
  // RN_f32(inter/uni) > 0.45f  <=>  fma(-TMID, uni, inter) > 0 in double,
  // TMID = (double)0.45f + 2^-26 (midpoint; ties round-to-even -> false).
  // Areas recomputed from boxes: bit-identical to reference's area values.
  {
    const double TMID = (double)0.45f + 0x1p-26;
    const int lw = wv & 3, half = wv >> 2;
    const int l = lw * 64 + lane;
    const bool lvalid = l < K;
    float4 lb = lvalid ? cbox[l] : z4;
    float lar = (lb.z - lb.x) * (lb.w - lb.y);
    const int jlim = (K < lw * 64 + 63) ? K : (lw * 64 + 63);
    const int jmid = jlim >> 1;
    const int jstart = half ? jmid : 0;
    const int jend = half ? jlim : jmid;
    for (int j0 = jstart; j0 < jend; j0 += 4) {
      const int jc = (jend - j0 < 4) ? (jend - j0) : 4;
      float4 jb[4];
#pragma unroll
      for (int q = 0; q < 4; ++q)
        if (q < jc) jb[q] = cbox[j0 + q];
      unsigned long long mres[4];
#pragma unroll
      for (int q = 0; q < 4; ++q) {
        if (q < jc) {  // jc wave-uniform
          float ja = (jb[q].z - jb[q].x) * (jb[q].w - jb[q].y);
          float xx1 = fmaxf(lb.x, jb[q].x);
          float yy1 = fmaxf(lb.y, jb[q].y);
          float xx2 = fminf(lb.z, jb[q].z);
          float yy2 = fminf(lb.w, jb[q].w);
          float iw = fmaxf(xx2 - xx1, 0.0f);
          float ih = fmaxf(yy2 - yy1, 0.0f);
          float inter = iw * ih;
          float uni = (lar - inter) + ja;  // area - inter + area[i]
          double tt = fma(-TMID, (double)uni, (double)inter);
          bool hit = lvalid & (l > (j0 + q)) & (tt > 0.0);
          mres[q] = __ballot((int)hit);
        }
      }
      if (lane == 0) {
#pragma unroll
        for (int q = 0; q < 4; ++q)
          if (q < jc) supp[(j0 + q) * 4 + lw] = mres[q];
      }
    }
    if (half == 1 && lane == 0)
      for (int j = jlim; j < K; ++j) supp[j * 4 + lw] = 0ull;
  }
  __syncthreads();

  // ---- wave0 chunk-register greedy: rows processed in 64-row chunks.
  //      Lane l holds ONLY the current chunk's row-l supp words (8 VGPRs,
  //      2x ds_read_b128 per chunk) -> inner loop is ffs + 8x v_readlane +
  //      mask ANDs, NO memory in the dependent chain. alive/kept masks are
  //      wave-uniform (SGPRs). Kept list rebuilt by popcount compaction. ----
  if (wv == 0) {
    unsigned long long a0, a1, a2, a3;
    {
      int c0 = K, c1 = K - 64, c2 = K - 128, c3 = K - 192;
      a0 = c0 <= 0 ? 0ull : (c0 >= 64 ? ~0ull : ((1ull << c0) - 1ull));
      a1 = c1 <= 0 ? 0ull : (c1 >= 64 ? ~0ull : ((1ull << c1) - 1ull));
      a2 = c2 <= 0 ? 0ull : (c2 >= 64 ? ~0ull : ((1ull << c2) - 1ull));
      a3 = c3 <= 0 ? 0ull : (c3 >= 64 ? ~0ull : ((1ull << c3) - 1ull));
    }
    unsigned long long k0 = 0ull, k1 = 0ull, k2 = 0ull, k3 = 0ull;
    const ulonglong2 zz = make_ulonglong2(0ull, 0ull);
    const ulonglong2* sp = (const ulonglong2*)supp;

#define GREEDY_CHUNK(W, AW, KW)                                              \
    if (AW) {                                                                \
      const int r = (W) * 64 + lane;                                         \
      ulonglong2 s01 = zz, s23 = zz;                                         \
      if (r < K) { s01 = sp[r * 2]; s23 = sp[r * 2 + 1]; }                   \
      while (AW) {                                                           \
        int sl = __ffsll(AW) - 1;                                            \
        KW |= 1ull << sl;                                                    \
        AW &= ~(1ull << sl);                                                 \
        unsigned long long q0 = rl64(s01.x, sl);                             \
        unsigned long long q1 = rl64(s01.y, sl);                             \
        unsigned long long q2 = rl64(s23.x, sl);                             \
        unsigned long long q3 = rl64(s23.y, sl);                             \
        a0 &= ~q0; a1 &= ~q1; a2 &= ~q2; a3 &= ~q3;                          \
      }                                                                      \
    }

    GREEDY_CHUNK(0, a0, k0)
    GREEDY_CHUNK(1, a1, k1)
    GREEDY_CHUNK(2, a2, k2)
    GREEDY_CHUNK(3, a3, k3)
#undef GREEDY_CHUNK

    // parallel compaction: kept[] in ascending rank order (== greedy order)
    const unsigned long long lmask = (1ull << lane) - 1ull;
    const int c0 = __popcll(k0), c1 = __popcll(k1), c2 = __popcll(k2);
    if ((k0 >> lane) & 1ull) kept[__popcll(k0 & lmask)] = lane;
    if ((k1 >> lane) & 1ull) kept[c0 + __popcll(k1 & lmask)] = 64 + lane;
    if ((k2 >> lane) & 1ull) kept[c0 + c1 + __popcll(k2 & lmask)] = 128 + lane;
    if ((k3 >> lane) & 1ull) kept[c0 + c1 + c2 + __popcll(k3 & lmask)] = 192 + lane;
    if (lane == 0) sKept = c0 + c1 + c2 + __popcll(k3);
  }
  __syncthreads();

  // ---- float4-packed per-row epilogue: pose loaded to regs (8x float4),
  //      row emitted as 10 shifted float4 stores (was 40 scalar stores).
  //      Rows are 160B-aligned so every store is a full dwordx4. ----
  const int nk = sKept;
  for (int t = tid; t < nk; t += NT) {
    int j = kept[t];
    int n = sIdx[j];
    float4* row4 = (float4*)(outSlab + (size_t)t * ROWW);
    float4 bx = cbox[j];
    const float4* p4 = (const float4*)(poseB + (size_t)n * NPOSE);  // early
    float4 pv[8];
#pragma unroll
    for (int q = 0; q < 8; ++q) pv[q] = p4[q];
    float l0 = lineB[(size_t)n * NLINE + 0];
    float l1 = lineB[(size_t)n * NLINE + 1];
    float l2 = lineB[(size_t)n * NLINE + 2];
    float sc = sScore[j];
    row4[0] = make_float4(sc, bx.x, bx.y, bx.z);
    row4[1] = make_float4(bx.w, pv[0].x, pv[0].y, pv[0].z);
    row4[2] = make_float4(pv[0].w, pv[1].x, pv[1].y, pv[1].z);
    row4[3] = make_float4(pv[1].w, pv[2].x, pv[2].y, pv[2].z);
    row4[4] = make_float4(pv[2].w, pv[3].x, pv[3].y, pv[3].z);
    row4[5] = make_float4(pv[3].w, pv[4].x, pv[4].y, pv[4].z);
    row4[6] = make_float4(pv[4].w, pv[5].x, pv[5].y, pv[5].z);
    row4[7] = make_float4(pv[5].w, pv[6].x, pv[6].y, pv[6].z);
    row4[8] = make_float4(pv[6].w, pv[7].x, pv[7].y, pv[7].z);
    row4[9] = make_float4(pv[7].w, l0, l1, l2);
  }
  {  // rows [nk, TOPK): 10 float4 per row
    const int zq = (TOPK - nk) * 10;
    float4* o4 = (float4*)(outSlab + (size_t)nk * ROWW);
    for (int q = tid; q < zq; q += NT) o4[q] = z4;
  }
}

// ---------------------------------------------------------------------------
extern "C" void kernel_launch(void* const* d_in, const int* in_sizes, int n_in,
                              void* d_out, int out_size, void* d_ws, size_t ws_size,
                              hipStream_t stream) {
  const float* loc  = (const float*)d_in[0];
  const float* conf = (const float*)d_in[1];
  const float* pose = (const float*)d_in[2];
  const float* line = (const float*)d_in[3];
  const float* dbox = (const float*)d_in[4];
  float* out = (float*)d_out;

  const size_t scoreBytes = (size_t)BB * CC * NN * sizeof(float);  // ~23.5 MB
  int mode = (ws_size >= scoreBytes) ? 1 : 0;
  float* scores = mode ? (float*)d_ws : nullptr;

  if (mode) {
    const int total = BB * NN;
    score_kernel<<<(total + 255) / 256, 256, 0, stream>>>(conf, scores);
  }
  nms_kernel<<<BB * CC, NT, 0, stream>>>(loc, conf, pose, line, dbox,
                                         scores, mode, out);
}